// Round 10
// baseline (3890.884 us; speedup 1.0000x reference)
//
#include <hip/hip_runtime.h>
#include <float.h>

#define BATCH 16
#define NPTS  65536
#define NP    64      // NUM_PATCHES
#define PS    32      // PATCH_SIZE
#define SLICES 4
#define SLICE_PTS (NPTS / SLICES)   // 16384
#define CAP   256                   // per (center,slice) cap (exp ~80)
#define AGENT __HIP_MEMORY_SCOPE_AGENT

// R9: mega-kernel fusion. Cross-round wall arithmetic (R3/R5/R6/R8) shows
// ~45-50us of dispatch-boundary overhead (~11-15us/boundary) — 2nd-largest
// cost after fps. Fuse fps+knn+merge into ONE kernel (2 dispatches total:
// memset + mega). Co-residency proof (deadlock safety): LB(256,4) caps
// VGPR<=128 (fps 88, knn ~68); static LDS 17.3KB <= 40KB/WG at 4 WG/CU;
// 16 waves/CU <= 32 -> all 1024 WGs resident simultaneously, so fps WGs
// can never be queued behind done[b]-waiters. Batch b -> XCD b%8 for all
// its WGs (blockIdx%8 == b%8). fps internals are v1 verbatim (frozen).

// Selection math (FPS argmax, KNN top-32) is float64 on f32 inputs (products
// of f32 exact in f64 -> bit-identical to numpy f64 regardless of FMA), with
// numpy expression order: ((a+b)+c), d2 = (c2+p2) - 2*dot, contract(off).
// Keys: trunc-48-bit f64 ordering bits | 16-bit index -> (dist, idx) lex order.

__device__ __forceinline__ unsigned long long enc64(double d) {
    unsigned long long u = (unsigned long long)__double_as_longlong(d);
    return u ^ ((u >> 63) ? 0xFFFFFFFFFFFFFFFFull : 0x8000000000000000ull);
}
__device__ __forceinline__ unsigned enc32(float f) {
    unsigned u = __float_as_uint(f);
    return u ^ ((u >> 31) ? 0xFFFFFFFFu : 0x80000000u);
}
__device__ __forceinline__ float dec32(unsigned e) {
    unsigned u = (e & 0x80000000u) ? (e ^ 0x80000000u) : ~e;
    return __uint_as_float(u);
}

#define SENT 0xFFFFFFFFFFFFFFFFull

__global__ __launch_bounds__(256, 4)
void mega_kernel(const float* __restrict__ pts,
                 float* __restrict__ centers,              // [16][64][3] out
                 float* __restrict__ patches,              // [16][64][32][3] out
                 unsigned long long* __restrict__ slots,   // [16][63][16] zeroed
                 int* __restrict__ done,                   // [16] zeroed
                 int* __restrict__ cntmw,                  // [16][16] zeroed
                 unsigned long long* __restrict__ gkeys)   // [1024][4][32]
{
    const int t    = threadIdx.x;
    const int lane = t & 63;
    const int wid  = t >> 6;             // 0..3
    const int b    = blockIdx.x & 15;
    const int w    = (blockIdx.x >> 4) & 15;
    const int s    = blockIdx.x >> 8;    // 0..3
    const float* __restrict__ P = pts + (size_t)b * NPTS * 3;

    __shared__ float centL[NP*3];                       // 768 B (fps->knn, s==0)
    __shared__ unsigned long long wbest[4], skey[16];   // fps mailbox staging
    union PoolKeys {
        unsigned pool[4][512];             // pass1/theta (8 KB)
        unsigned long long keys[4][CAP];   // phase 3 (8 KB) — pool dead by then
    };
    __shared__ PoolKeys pk;
    __shared__ float    theta4[4];
    __shared__ int      cnt4[4];
    __shared__ unsigned idxbuf[4][CAP];                 // 4 KB
    __shared__ unsigned long long mk[4][SLICES*PS];     // 4 KB (merge)
    __shared__ int amMerger;

    if (s == 0) {
        // ============ FPS phase (this WG is fps v1's (b, wg=w)) ============
#pragma clang fp contract(off)
        float x[16], y[16], z[16];
        double md[16];
        const int gi0 = w * 4096 + t;
#pragma unroll
        for (int k = 0; k < 16; ++k) {
            int i = gi0 + (k << 8);
            x[k] = P[3*i+0]; y[k] = P[3*i+1]; z[k] = P[3*i+2];
            md[k] = DBL_MAX;
        }
        double cx = (double)P[0], cy = (double)P[1], cz = (double)P[2]; // start 0
        if (t == 0) {
            centL[0] = P[0]; centL[1] = P[1]; centL[2] = P[2];
            if (w == 0) {
                float* c0 = centers + b * (NP*3);
                c0[0] = P[0]; c0[1] = P[1]; c0[2] = P[2];
            }
        }
        unsigned long long* slot_it = slots + (size_t)b * 63 * 16;
        for (int it = 0; it < NP - 1; ++it) {
            double bd = -1.0; int bi = 0;
#pragma unroll
            for (int k = 0; k < 16; ++k) {
                double dx = (double)x[k] - cx;
                double dy = (double)y[k] - cy;
                double dz = (double)z[k] - cz;
                double d  = (dx*dx + dy*dy) + dz*dz;   // numpy add order
                double m  = fmin(md[k], d);
                md[k] = m;
                if (m > bd) { bd = m; bi = gi0 + (k << 8); } // strict >: first idx
            }
            unsigned long long db  = (unsigned long long)__double_as_longlong(bd);
            unsigned long long key = 0x8000000000000000ull
                                   | (db & 0xFFFFFFFFFFFF0000ull)
                                   | (unsigned long long)((~bi) & 0xFFFF);
#pragma unroll
            for (int off = 32; off > 0; off >>= 1) {
                unsigned long long o = __shfl_xor(key, off, 64);
                if (o > key) key = o;
            }
            if ((t & 63) == 0) wbest[t >> 6] = key;
            __syncthreads();                                   // bar1
            if (t == 0) {
                unsigned long long k0 = wbest[0];
                if (wbest[1] > k0) k0 = wbest[1];
                if (wbest[2] > k0) k0 = wbest[2];
                if (wbest[3] > k0) k0 = wbest[3];
                __hip_atomic_store(slot_it + w, k0, __ATOMIC_RELAXED, AGENT);
            }
            if (t < 16) {
                unsigned long long v;
                v = __hip_atomic_load(slot_it + t, __ATOMIC_RELAXED, AGENT);
                while (v == 0) {
                    __builtin_amdgcn_s_sleep(1);
                    v = __hip_atomic_load(slot_it + t, __ATOMIC_RELAXED, AGENT);
                }
                skey[t] = v;
            }
            __syncthreads();                                   // bar2
            unsigned long long bk = skey[0];
#pragma unroll
            for (int j = 1; j < 16; ++j) if (skey[j] > bk) bk = skey[j];
            int sel = (int)((~bk) & 0xFFFFull);
            cx = (double)P[3*sel+0]; cy = (double)P[3*sel+1]; cz = (double)P[3*sel+2];
            if (t == 0) {
                centL[3*(it+1)+0] = P[3*sel+0];
                centL[3*(it+1)+1] = P[3*sel+1];
                centL[3*(it+1)+2] = P[3*sel+2];
                if (w == 0) {
                    float* c = centers + b*(NP*3) + (it+1)*3;
                    c[0] = P[3*sel+0]; c[1] = P[3*sel+1]; c[2] = P[3*sel+2];
                }
            }
            slot_it += 16;
            // no trailing barrier: next round's bar1 orders skey/wbest reuse
        }
        __syncthreads();   // centL complete (t0's round-62 write) before knn reads
        if (w == 0 && t == 0)
            __hip_atomic_store(done + b, 1, __ATOMIC_RELEASE, AGENT);
        // (release publishes wg0's centers stores; barrier already drained vmem)
    } else {
        // ============ wait for this batch's centers ============
        if (t == 0) {
            while (__hip_atomic_load(done + b, __ATOMIC_ACQUIRE, AGENT) == 0)
                __builtin_amdgcn_s_sleep(16);
        }
        __syncthreads();   // acquire (L1-inv) by t0 ordered before all lanes' loads
    }

    // ================= KNN phase (R8 logic, slice s of batch b) =================
    const int sbase = s * SLICE_PTS;
    const float4* __restrict__ P4 = (const float4*)(P + 3 * sbase);

    float m2x[4], m2y[4], m2z[4], c2f[4];
#pragma unroll
    for (int g = 0; g < 4; ++g) {
        float cx_, cy_, cz_;
        if (s == 0) {
            cx_ = centL[3*(w*4+g)+0]; cy_ = centL[3*(w*4+g)+1]; cz_ = centL[3*(w*4+g)+2];
        } else {
            int c = b * NP + w * 4 + g;
            cx_ = centers[3*c+0]; cy_ = centers[3*c+1]; cz_ = centers[3*c+2];
        }
        c2f[g] = cx_*cx_ + cy_*cy_ + cz_*cz_;
        m2x[g] = -2.0f*cx_; m2y[g] = -2.0f*cy_; m2z[g] = -2.0f*cz_;
    }

    // ---- pass 1: per-thread top-2 (f32), 4 pts/iter, prefetch k+1 ----
    float s0[4], s1[4];
#pragma unroll
    for (int g = 0; g < 4; ++g) { s0[g] = FLT_MAX; s1[g] = FLT_MAX; }
    {
        float4 A = P4[3*t], B = P4[3*t+1], C = P4[3*t+2];
        for (int k = 0; k < SLICE_PTS/1024; ++k) {       // 16 iterations
            int vb = ((k+1) & 15)*768 + 3*t;             // wrap: last prefetch dropped
            float4 An = P4[vb], Bn = P4[vb+1], Cn = P4[vb+2];
            float qx[4] = {A.x, A.w, B.z, C.y};
            float qy[4] = {A.y, B.x, B.w, C.z};
            float qz[4] = {A.z, B.y, C.x, C.w};
#pragma unroll
            for (int j = 0; j < 4; ++j) {
                float px = qx[j], py = qy[j], pz = qz[j];
                float p2 = px*px + py*py + pz*pz;
#pragma unroll
                for (int g = 0; g < 4; ++g) {
                    float d2 = fmaf(m2x[g], px, fmaf(m2y[g], py, fmaf(m2z[g], pz, c2f[g]))) + p2;
                    s1[g] = __builtin_amdgcn_fmed3f(s0[g], s1[g], d2);   // exact 2nd-min
                    s0[g] = fminf(s0[g], d2);
                }
            }
            A = An; B = Bn; C = Cn;
        }
    }
#pragma unroll
    for (int g = 0; g < 4; ++g) {
        pk.pool[g][t]       = enc32(s0[g]);
        pk.pool[g][256 + t] = enc32(s1[g]);
    }
    if (t < 4) cnt4[t] = 0;
    __syncthreads();

    // ---- theta: wave wid finds 32nd smallest of pool[wid][0..511] ----
    {
        const int g = wid;
        unsigned e[8];
#pragma unroll
        for (int j = 0; j < 8; ++j) e[j] = pk.pool[g][j * 64 + lane];  // conflict-free
        unsigned ans = 0;
        for (int bit = 31; bit >= 0; --bit) {
            unsigned test = ans | ((1u << bit) - 1u);
            int cnt = 0;
#pragma unroll
            for (int j = 0; j < 8; ++j)
                cnt += (int)__popcll(__ballot(e[j] <= test));
            if (cnt < 32) ans |= (1u << bit);
        }
        if (lane == 0) theta4[g] = dec32(ans) + 4.0e-3f;
    }
    __syncthreads();
    float th[4];
#pragma unroll
    for (int g = 0; g < 4; ++g) th[g] = theta4[g];

    // ---- pass 2: f32 rescan (identical d2), atomicAdd compaction ----
    {
        float4 A = P4[3*t], B = P4[3*t+1], C = P4[3*t+2];
        for (int k = 0; k < SLICE_PTS/1024; ++k) {
            int vb = ((k+1) & 15)*768 + 3*t;
            float4 An = P4[vb], Bn = P4[vb+1], Cn = P4[vb+2];
            float qx[4] = {A.x, A.w, B.z, C.y};
            float qy[4] = {A.y, B.x, B.w, C.z};
            float qz[4] = {A.z, B.y, C.x, C.w};
            int ib = sbase + (k << 10) + (t << 2);
#pragma unroll
            for (int j = 0; j < 4; ++j) {
                float px = qx[j], py = qy[j], pz = qz[j];
                float p2 = px*px + py*py + pz*pz;
#pragma unroll
                for (int g = 0; g < 4; ++g) {
                    float d2 = fmaf(m2x[g], px, fmaf(m2y[g], py, fmaf(m2z[g], pz, c2f[g]))) + p2;
                    if (d2 <= th[g]) {
                        int pos = atomicAdd(&cnt4[g], 1);
                        if (pos < CAP) idxbuf[g][pos] = (unsigned)(ib + j);
                    }
                }
            }
            A = An; B = Bn; C = Cn;
        }
    }
    __syncthreads();   // idxbuf/cnt4 complete; pool dead -> pk.keys reusable

    // ---- phase 3: wave wid -> center wid: f64 keys + counting-rank top-32 ----
    {
        const int g = wid;
        int n = cnt4[g]; if (n > CAP) n = CAP;
        double cxd, cyd, czd, c2d;
        {
#pragma clang fp contract(off)
            cxd = -0.5*(double)m2x[g]; cyd = -0.5*(double)m2y[g]; czd = -0.5*(double)m2z[g];
            c2d = (cxd*cxd + cyd*cyd) + czd*czd;
        }
        unsigned long long rg[4];
#pragma unroll
        for (int j = 0; j < 4; ++j) {
            int p_ = lane + 64*j;
            if (p_ < n) {
                unsigned i = idxbuf[g][p_];
                double d2x;
                {
#pragma clang fp contract(off)
                    double px_ = (double)P[3*i+0];
                    double py_ = (double)P[3*i+1];
                    double pz_ = (double)P[3*i+2];
                    double p2_ = (px_*px_ + py_*py_) + pz_*pz_;
                    double dt_ = (cxd*px_ + cyd*py_) + czd*pz_;
                    d2x = (c2d + p2_) - 2.0*dt_;
                }
                rg[j] = (enc64(d2x) & 0xFFFFFFFFFFFF0000ull)
                      | (unsigned long long)(i & 0xFFFF);
                pk.keys[g][p_] = rg[j];
            } else rg[j] = SENT;
        }
        const int c = b * NP + w * 4 + g;
        int rk[4] = {0, 0, 0, 0};
        for (int p = 0; p < n; ++p) {
            unsigned long long kj = pk.keys[g][p];   // broadcast read
            rk[0] += (kj < rg[0]);
            rk[1] += (kj < rg[1]);
            rk[2] += (kj < rg[2]);
            rk[3] += (kj < rg[3]);
        }
        unsigned long long* gout = gkeys + ((size_t)c * SLICES + s) * PS;
#pragma unroll
        for (int j = 0; j < 4; ++j)
            if (lane + 64*j < n && rk[j] < PS) gout[rk[j]] = rg[j];
        // theta guarantees n >= 32 -> ranks 0..31 all filled (keys unique).
    }
    __syncthreads();   // barrier drains all waves' gkeys stores (vmcnt(0))

    // ---- merge (absorbed knn_merge): last slice-WG of (b,w) merges ----
    if (t == 0) {
        int old = __hip_atomic_fetch_add(cntmw + b*16 + w, 1, __ATOMIC_ACQ_REL, AGENT);
        amMerger = (old == SLICES - 1);
    }
    __syncthreads();
    if (amMerger) {
        // wave wid merges center c = b*64 + w*4 + wid: 128 keys, counting-rank
        const int c = b * NP + w * 4 + wid;
        const unsigned long long* gk = gkeys + (size_t)c * (SLICES*PS);
        unsigned long long rg0 = gk[lane];
        unsigned long long rg1 = gk[64 + lane];
        mk[wid][lane]      = rg0;
        mk[wid][64 + lane] = rg1;
        int r0 = 0, r1 = 0;
#pragma unroll 4
        for (int p = 0; p < SLICES*PS; ++p) {
            unsigned long long kj = mk[wid][p];      // broadcast read
            r0 += (kj < rg0);
            r1 += (kj < rg1);
        }
        const float cx_ = -0.5f * m2x[wid];   // exact (pow2 scalings)
        const float cy_ = -0.5f * m2y[wid];
        const float cz_ = -0.5f * m2z[wid];
        if (r0 < PS) {
            int i = (int)(rg0 & 0xFFFFull);
            float* o = patches + (((size_t)c * PS) + r0) * 3;
            o[0] = P[3*i+0] - cx_;
            o[1] = P[3*i+1] - cy_;
            o[2] = P[3*i+2] - cz_;
        }
        if (r1 < PS) {
            int i = (int)(rg1 & 0xFFFFull);
            float* o = patches + (((size_t)c * PS) + r1) * 3;
            o[0] = P[3*i+0] - cx_;
            o[1] = P[3*i+1] - cy_;
            o[2] = P[3*i+2] - cz_;
        }
    }
}

extern "C" void kernel_launch(void* const* d_in, const int* in_sizes, int n_in,
                              void* d_out, int out_size, void* d_ws, size_t ws_size,
                              hipStream_t stream)
{
    const float* pts = (const float*)d_in[0];
    float* out      = (float*)d_out;
    float* patches  = out;                          // [16][64][32][3] = 98304
    float* centers  = out + (size_t)BATCH*NP*PS*3;  // [16][64][3]     = 3072

    // workspace layout (zeroed region = [0, 131072)):
    unsigned long long* slots = (unsigned long long*)d_ws;                 // 129024 B
    int* done  = (int*)((char*)d_ws + 129024);                             // 64 B
    int* cntmw = (int*)((char*)d_ws + 129088);                             // 1024 B
    unsigned long long* gkeys = (unsigned long long*)((char*)d_ws + 131072); // 1 MB

    (void)hipMemsetAsync(d_ws, 0, 131072, stream);
    mega_kernel<<<dim3(1024), dim3(256), 0, stream>>>(
        pts, centers, patches, slots, done, cntmw, gkeys);
}

// Round 11
// 223.438 us; speedup vs baseline: 17.4137x; 17.4137x over previous
//
#include <hip/hip_runtime.h>
#include <float.h>

#define BATCH 16
#define NPTS  65536
#define NP    64      // NUM_PATCHES
#define PS    32      // PATCH_SIZE
#define SLICES 4
#define SLICE_PTS (NPTS / SLICES)   // 16384
#define CAP   256                   // per (center,slice) cap (exp ~80)
#define AGENT __HIP_MEMORY_SCOPE_AGENT

// R11: partial fusion. R10's full fusion regressed 18x — unified regalloc
// across fps+knn forced VGPR 88->64 and spilled FPS state (WRITE_SIZE 516KB
// ->10MB). Fix: keep fps standalone (frozen v1, 88 VGPR); fuse ONLY merge
// into knn_pass via the cntmw last-arriver pattern (validated correct in
// R10's run; deadlock-free at any residency — losers exit, nobody waits).
// Saves one dispatch boundary (~12us) + absorbs the merge dispatch (~3us).

// Selection math (FPS argmax, KNN top-32) is float64 on f32 inputs (products
// of f32 exact in f64 -> bit-identical to numpy f64 regardless of FMA), with
// numpy expression order: ((a+b)+c), d2 = (c2+p2) - 2*dot, contract(off).
// Keys: trunc-48-bit f64 ordering bits | 16-bit index -> (dist, idx) lex order.

__device__ __forceinline__ unsigned long long enc64(double d) {
    unsigned long long u = (unsigned long long)__double_as_longlong(d);
    return u ^ ((u >> 63) ? 0xFFFFFFFFFFFFFFFFull : 0x8000000000000000ull);
}
__device__ __forceinline__ unsigned enc32(float f) {
    unsigned u = __float_as_uint(f);
    return u ^ ((u >> 31) ? 0xFFFFFFFFu : 0x80000000u);
}
__device__ __forceinline__ float dec32(unsigned e) {
    unsigned u = (e & 0x80000000u) ? (e ^ 0x80000000u) : ~e;
    return __uint_as_float(u);
}

#define SENT 0xFFFFFFFFFFFFFFFFull

// ---------------------------------------------------------------------------
// FPS (v1, known-good 117us — PERMANENT: sync/fusion restructure 0-for-4,
// R2/R5/R10 post-mortems). 16 WGs per batch (blockIdx = wg*16+b -> all WGs
// of batch b on XCD b%8), 256 threads, 16 pts/thread in VGPRs. Relaxed agent
// atomics only. 2 barriers per round.
// ---------------------------------------------------------------------------
__global__ __launch_bounds__(256, 2)
void fps_kernel(const float* __restrict__ pts,
                float* __restrict__ centers,               // [16][64][3]
                unsigned long long* __restrict__ slots)    // [16][63][16], zeroed
{
#pragma clang fp contract(off)
    const int b  = blockIdx.x & 15;
    const int wg = blockIdx.x >> 4;
    const int t  = threadIdx.x;
    const float* __restrict__ P = pts + (size_t)b * NPTS * 3;

    float x[16], y[16], z[16];
    double md[16];
    const int gi0 = wg * 4096 + t;
#pragma unroll
    for (int k = 0; k < 16; ++k) {
        int i = gi0 + (k << 8);
        x[k] = P[3*i+0]; y[k] = P[3*i+1]; z[k] = P[3*i+2];
        md[k] = DBL_MAX;
    }

    double cx = (double)P[0], cy = (double)P[1], cz = (double)P[2]; // start idx 0
    if (wg == 0 && t == 0) {
        float* c0 = centers + b * (NP*3);
        c0[0] = P[0]; c0[1] = P[1]; c0[2] = P[2];
    }

    __shared__ unsigned long long wbest[4];
    __shared__ unsigned long long skey[16];

    unsigned long long* slot_it = slots + (size_t)b * 63 * 16;

    for (int it = 0; it < NP - 1; ++it) {
        double bd = -1.0; int bi = 0;
#pragma unroll
        for (int k = 0; k < 16; ++k) {
            double dx = (double)x[k] - cx;
            double dy = (double)y[k] - cy;
            double dz = (double)z[k] - cz;
            double d  = (dx*dx + dy*dy) + dz*dz;   // numpy add order (products exact)
            double m  = fmin(md[k], d);
            md[k] = m;
            if (m > bd) { bd = m; bi = gi0 + (k << 8); }  // strict >: first index wins
        }
        unsigned long long db  = (unsigned long long)__double_as_longlong(bd); // bd>=0
        unsigned long long key = 0x8000000000000000ull
                               | (db & 0xFFFFFFFFFFFF0000ull)
                               | (unsigned long long)((~bi) & 0xFFFF);
#pragma unroll
        for (int off = 32; off > 0; off >>= 1) {
            unsigned long long o = __shfl_xor(key, off, 64);
            if (o > key) key = o;
        }
        if ((t & 63) == 0) wbest[t >> 6] = key;
        __syncthreads();                                   // bar1
        if (t == 0) {
            unsigned long long k0 = wbest[0];
            if (wbest[1] > k0) k0 = wbest[1];
            if (wbest[2] > k0) k0 = wbest[2];
            if (wbest[3] > k0) k0 = wbest[3];
            __hip_atomic_store(slot_it + wg, k0, __ATOMIC_RELAXED, AGENT);
        }
        if (t < 16) {
            unsigned long long v;
            v = __hip_atomic_load(slot_it + t, __ATOMIC_RELAXED, AGENT);
            while (v == 0) {
                __builtin_amdgcn_s_sleep(1);
                v = __hip_atomic_load(slot_it + t, __ATOMIC_RELAXED, AGENT);
            }
            skey[t] = v;
        }
        __syncthreads();                                   // bar2
        unsigned long long bk = skey[0];
#pragma unroll
        for (int j = 1; j < 16; ++j) if (skey[j] > bk) bk = skey[j];
        int sel = (int)((~bk) & 0xFFFFull);
        cx = (double)P[3*sel+0]; cy = (double)P[3*sel+1]; cz = (double)P[3*sel+2];
        if (wg == 0 && t == 0) {
            float* c = centers + b*(NP*3) + (it+1)*3;
            c[0] = P[3*sel+0]; c[1] = P[3*sel+1]; c[2] = P[3*sel+2];
        }
        slot_it += 16;
        // no trailing barrier: next round's bar1 orders skey/wbest reuse
    }
}

// ---------------------------------------------------------------------------
// KNN pass + merge (R8 knn logic verbatim; merge epilogue absorbed via cntmw
// last-arriver, validated in R10). 1024 WGs x 256 thr. blockIdx: b=&15,
// w=(>>4)&15, s=>>8 (slice of 16384). Pass 1: per-thread top-2 (fma-chain
// d2, med3) -> pool -> theta = 32nd + 4e-3. Pass 2: identical d2, atomicAdd
// compaction (order-free). Phase 3: exact f64 keys (4/lane), counting-rank
// top-32 -> gkeys. Epilogue: t0 fetch_add(ACQ_REL) on cntmw[b][w]; the 4th
// arriver (release publishes its gkeys; acquire sees others') counting-ranks
// the 128 keys and writes patch rows. Losers exit — no waiting anywhere.
// ---------------------------------------------------------------------------
__global__ __launch_bounds__(256, 4)
void knn_fused(const float* __restrict__ pts,
               const float* __restrict__ centers,
               float* __restrict__ patches,               // [16][64][32][3] out
               int* __restrict__ cntmw,                   // [16][16] zeroed
               unsigned long long* __restrict__ gkeys)    // [1024][4][32]
{
    const int t    = threadIdx.x;
    const int lane = t & 63;
    const int wid  = t >> 6;             // 0..3
    const int b    = blockIdx.x & 15;
    const int w    = (blockIdx.x >> 4) & 15;
    const int s    = blockIdx.x >> 8;    // 0..3
    const float* __restrict__ P = pts + (size_t)b * NPTS * 3;
    const int sbase = s * SLICE_PTS;
    const float4* __restrict__ P4 = (const float4*)(P + 3 * sbase);

    float m2x[4], m2y[4], m2z[4], c2f[4];
#pragma unroll
    for (int g = 0; g < 4; ++g) {
        int c = b * NP + w * 4 + g;
        float cx = centers[3*c+0], cy = centers[3*c+1], cz = centers[3*c+2];
        c2f[g] = cx*cx + cy*cy + cz*cz;
        m2x[g] = -2.0f*cx; m2y[g] = -2.0f*cy; m2z[g] = -2.0f*cz;
    }

    union PoolKeys {
        unsigned pool[4][512];             // pass1/theta (8 KB)
        unsigned long long keys[4][CAP];   // phase 3 (8 KB) — pool dead by then
    };
    __shared__ PoolKeys pk;
    __shared__ float    theta4[4];
    __shared__ int      cnt4[4];
    __shared__ unsigned idxbuf[4][CAP];    // 4 KB
    __shared__ unsigned long long mk[4][SLICES*PS];   // 4 KB (merge)
    __shared__ int amMerger;

    // ---- pass 1: per-thread top-2 (f32), 4 pts/iter, prefetch k+1 ----
    float s0[4], s1[4];
#pragma unroll
    for (int g = 0; g < 4; ++g) { s0[g] = FLT_MAX; s1[g] = FLT_MAX; }
    {
        float4 A = P4[3*t], B = P4[3*t+1], C = P4[3*t+2];
        for (int k = 0; k < SLICE_PTS/1024; ++k) {       // 16 iterations
            int vb = ((k+1) & 15)*768 + 3*t;             // wrap: last prefetch dropped
            float4 An = P4[vb], Bn = P4[vb+1], Cn = P4[vb+2];
            float qx[4] = {A.x, A.w, B.z, C.y};
            float qy[4] = {A.y, B.x, B.w, C.z};
            float qz[4] = {A.z, B.y, C.x, C.w};
#pragma unroll
            for (int j = 0; j < 4; ++j) {
                float px = qx[j], py = qy[j], pz = qz[j];
                float p2 = px*px + py*py + pz*pz;
#pragma unroll
                for (int g = 0; g < 4; ++g) {
                    float d2 = fmaf(m2x[g], px, fmaf(m2y[g], py, fmaf(m2z[g], pz, c2f[g]))) + p2;
                    s1[g] = __builtin_amdgcn_fmed3f(s0[g], s1[g], d2);   // exact 2nd-min
                    s0[g] = fminf(s0[g], d2);
                }
            }
            A = An; B = Bn; C = Cn;
        }
    }
#pragma unroll
    for (int g = 0; g < 4; ++g) {
        pk.pool[g][t]       = enc32(s0[g]);
        pk.pool[g][256 + t] = enc32(s1[g]);
    }
    if (t < 4) cnt4[t] = 0;
    __syncthreads();

    // ---- theta: wave wid finds 32nd smallest of pool[wid][0..511] ----
    {
        const int g = wid;
        unsigned e[8];
#pragma unroll
        for (int j = 0; j < 8; ++j) e[j] = pk.pool[g][j * 64 + lane];  // conflict-free
        unsigned ans = 0;
        for (int bit = 31; bit >= 0; --bit) {
            unsigned test = ans | ((1u << bit) - 1u);
            int cnt = 0;
#pragma unroll
            for (int j = 0; j < 8; ++j)
                cnt += (int)__popcll(__ballot(e[j] <= test));
            if (cnt < 32) ans |= (1u << bit);
        }
        if (lane == 0) theta4[g] = dec32(ans) + 4.0e-3f;
    }
    __syncthreads();
    float th[4];
#pragma unroll
    for (int g = 0; g < 4; ++g) th[g] = theta4[g];

    // ---- pass 2: f32 rescan (identical d2), atomicAdd compaction ----
    {
        float4 A = P4[3*t], B = P4[3*t+1], C = P4[3*t+2];
        for (int k = 0; k < SLICE_PTS/1024; ++k) {
            int vb = ((k+1) & 15)*768 + 3*t;
            float4 An = P4[vb], Bn = P4[vb+1], Cn = P4[vb+2];
            float qx[4] = {A.x, A.w, B.z, C.y};
            float qy[4] = {A.y, B.x, B.w, C.z};
            float qz[4] = {A.z, B.y, C.x, C.w};
            int ib = sbase + (k << 10) + (t << 2);
#pragma unroll
            for (int j = 0; j < 4; ++j) {
                float px = qx[j], py = qy[j], pz = qz[j];
                float p2 = px*px + py*py + pz*pz;
#pragma unroll
                for (int g = 0; g < 4; ++g) {
                    float d2 = fmaf(m2x[g], px, fmaf(m2y[g], py, fmaf(m2z[g], pz, c2f[g]))) + p2;
                    if (d2 <= th[g]) {
                        int pos = atomicAdd(&cnt4[g], 1);
                        if (pos < CAP) idxbuf[g][pos] = (unsigned)(ib + j);
                    }
                }
            }
            A = An; B = Bn; C = Cn;
        }
    }
    __syncthreads();   // idxbuf/cnt4 complete; pool dead -> pk.keys reusable

    // ---- phase 3: wave wid -> center wid: f64 keys + counting-rank top-32 ----
    {
        const int g = wid;
        int n = cnt4[g]; if (n > CAP) n = CAP;
        double cxd, cyd, czd, c2d;
        {
#pragma clang fp contract(off)
            cxd = -0.5*(double)m2x[g]; cyd = -0.5*(double)m2y[g]; czd = -0.5*(double)m2z[g];
            c2d = (cxd*cxd + cyd*cyd) + czd*czd;
        }
        unsigned long long rg[4];
#pragma unroll
        for (int j = 0; j < 4; ++j) {
            int p_ = lane + 64*j;
            if (p_ < n) {
                unsigned i = idxbuf[g][p_];
                double d2x;
                {
#pragma clang fp contract(off)
                    double px_ = (double)P[3*i+0];
                    double py_ = (double)P[3*i+1];
                    double pz_ = (double)P[3*i+2];
                    double p2_ = (px_*px_ + py_*py_) + pz_*pz_;
                    double dt_ = (cxd*px_ + cyd*py_) + czd*pz_;
                    d2x = (c2d + p2_) - 2.0*dt_;
                }
                rg[j] = (enc64(d2x) & 0xFFFFFFFFFFFF0000ull)
                      | (unsigned long long)(i & 0xFFFF);
                pk.keys[g][p_] = rg[j];
            } else rg[j] = SENT;
        }
        const int c = b * NP + w * 4 + g;
        int rk[4] = {0, 0, 0, 0};
        for (int p = 0; p < n; ++p) {
            unsigned long long kj = pk.keys[g][p];   // broadcast read
            rk[0] += (kj < rg[0]);
            rk[1] += (kj < rg[1]);
            rk[2] += (kj < rg[2]);
            rk[3] += (kj < rg[3]);
        }
        unsigned long long* gout = gkeys + ((size_t)c * SLICES + s) * PS;
#pragma unroll
        for (int j = 0; j < 4; ++j)
            if (lane + 64*j < n && rk[j] < PS) gout[rk[j]] = rg[j];
        // theta guarantees n >= 32 -> ranks 0..31 all filled (keys unique).
    }
    __syncthreads();   // all waves' gkeys stores issued (barrier drains vmem)

    // ---- merge: 4th-arriving WG of (b,w) counting-ranks 128 keys ----
    if (t == 0) {
        int old = __hip_atomic_fetch_add(cntmw + b*16 + w, 1, __ATOMIC_ACQ_REL, AGENT);
        amMerger = (old == SLICES - 1);
    }
    __syncthreads();
    if (amMerger) {
        const int c = b * NP + w * 4 + wid;
        const unsigned long long* gk = gkeys + (size_t)c * (SLICES*PS);
        unsigned long long rg0 = gk[lane];
        unsigned long long rg1 = gk[64 + lane];
        mk[wid][lane]      = rg0;
        mk[wid][64 + lane] = rg1;
        int r0 = 0, r1 = 0;
#pragma unroll 4
        for (int p = 0; p < SLICES*PS; ++p) {
            unsigned long long kj = mk[wid][p];      // broadcast read
            r0 += (kj < rg0);
            r1 += (kj < rg1);
        }
        const float cx_ = -0.5f * m2x[wid];   // exact (pow2 scalings)
        const float cy_ = -0.5f * m2y[wid];
        const float cz_ = -0.5f * m2z[wid];
        if (r0 < PS) {
            int i = (int)(rg0 & 0xFFFFull);
            float* o = patches + (((size_t)c * PS) + r0) * 3;
            o[0] = P[3*i+0] - cx_;
            o[1] = P[3*i+1] - cy_;
            o[2] = P[3*i+2] - cz_;
        }
        if (r1 < PS) {
            int i = (int)(rg1 & 0xFFFFull);
            float* o = patches + (((size_t)c * PS) + r1) * 3;
            o[0] = P[3*i+0] - cx_;
            o[1] = P[3*i+1] - cy_;
            o[2] = P[3*i+2] - cz_;
        }
    }
}

extern "C" void kernel_launch(void* const* d_in, const int* in_sizes, int n_in,
                              void* d_out, int out_size, void* d_ws, size_t ws_size,
                              hipStream_t stream)
{
    const float* pts = (const float*)d_in[0];
    float* out      = (float*)d_out;
    float* patches  = out;                          // [16][64][32][3] = 98304
    float* centers  = out + (size_t)BATCH*NP*PS*3;  // [16][64][3]     = 3072

    // workspace layout (zeroed region = [0, 130048)):
    unsigned long long* slots = (unsigned long long*)d_ws;                 // 129024 B
    int* cntmw = (int*)((char*)d_ws + 129024);                             // 1024 B
    unsigned long long* gkeys = (unsigned long long*)((char*)d_ws + 131072); // 1 MB

    (void)hipMemsetAsync(d_ws, 0, 130048, stream);
    fps_kernel<<<dim3(256), dim3(256), 0, stream>>>(pts, centers, slots);
    knn_fused<<<dim3(1024), dim3(256), 0, stream>>>(pts, centers, patches, cntmw, gkeys);
}

// Round 12
// 208.554 us; speedup vs baseline: 18.6565x; 1.0714x over previous
//
#include <hip/hip_runtime.h>
#include <float.h>

#define BATCH 16
#define NPTS  65536
#define NP    64      // NUM_PATCHES
#define PS    32      // PATCH_SIZE
#define SLICES 4
#define SLICE_PTS (NPTS / SLICES)   // 16384
#define CAP   256                   // per (center,slice) cap (exp ~90)
#define AGENT __HIP_MEMORY_SCOPE_AGENT

// R12: revert fusion (R9-R11: 0-for-3; residual ~50us is fixed harness
// overhead, not per-boundary). Exact R8 3-kernel structure + one diet rider:
// pass-1 keeps per-thread TOP-1 only (was top-2). Pool = 256 thread-minima,
// a <=1-per-thread subset of true distances -> its 32nd order statistic >=
// overall 32nd -> theta still admits all 32 true neighbors; candidate growth
// ~+5-10 (<< CAP). Saves med3 + pool store per (pt,g), halves theta radix.

// Selection math (FPS argmax, KNN top-32) is float64 on f32 inputs (products
// of f32 exact in f64 -> bit-identical to numpy f64 regardless of FMA), with
// numpy expression order: ((a+b)+c), d2 = (c2+p2) - 2*dot, contract(off).
// Keys: trunc-48-bit f64 ordering bits | 16-bit index -> (dist, idx) lex order.

__device__ __forceinline__ unsigned long long enc64(double d) {
    unsigned long long u = (unsigned long long)__double_as_longlong(d);
    return u ^ ((u >> 63) ? 0xFFFFFFFFFFFFFFFFull : 0x8000000000000000ull);
}
__device__ __forceinline__ unsigned enc32(float f) {
    unsigned u = __float_as_uint(f);
    return u ^ ((u >> 31) ? 0xFFFFFFFFu : 0x80000000u);
}
__device__ __forceinline__ float dec32(unsigned e) {
    unsigned u = (e & 0x80000000u) ? (e ^ 0x80000000u) : ~e;
    return __uint_as_float(u);
}

#define SENT 0xFFFFFFFFFFFFFFFFull

// ---------------------------------------------------------------------------
// FPS (v1, known-good 117us — PERMANENT: sync/fusion restructure 0-for-4,
// R2/R5/R10 post-mortems). 16 WGs per batch (blockIdx = wg*16+b -> all WGs
// of batch b on XCD b%8), 256 threads, 16 pts/thread in VGPRs. Relaxed agent
// atomics only. 2 barriers per round.
// ---------------------------------------------------------------------------
__global__ __launch_bounds__(256, 2)
void fps_kernel(const float* __restrict__ pts,
                float* __restrict__ centers,               // [16][64][3]
                unsigned long long* __restrict__ slots)    // [16][63][16], zeroed
{
#pragma clang fp contract(off)
    const int b  = blockIdx.x & 15;
    const int wg = blockIdx.x >> 4;
    const int t  = threadIdx.x;
    const float* __restrict__ P = pts + (size_t)b * NPTS * 3;

    float x[16], y[16], z[16];
    double md[16];
    const int gi0 = wg * 4096 + t;
#pragma unroll
    for (int k = 0; k < 16; ++k) {
        int i = gi0 + (k << 8);
        x[k] = P[3*i+0]; y[k] = P[3*i+1]; z[k] = P[3*i+2];
        md[k] = DBL_MAX;
    }

    double cx = (double)P[0], cy = (double)P[1], cz = (double)P[2]; // start idx 0
    if (wg == 0 && t == 0) {
        float* c0 = centers + b * (NP*3);
        c0[0] = P[0]; c0[1] = P[1]; c0[2] = P[2];
    }

    __shared__ unsigned long long wbest[4];
    __shared__ unsigned long long skey[16];

    unsigned long long* slot_it = slots + (size_t)b * 63 * 16;

    for (int it = 0; it < NP - 1; ++it) {
        double bd = -1.0; int bi = 0;
#pragma unroll
        for (int k = 0; k < 16; ++k) {
            double dx = (double)x[k] - cx;
            double dy = (double)y[k] - cy;
            double dz = (double)z[k] - cz;
            double d  = (dx*dx + dy*dy) + dz*dz;   // numpy add order (products exact)
            double m  = fmin(md[k], d);
            md[k] = m;
            if (m > bd) { bd = m; bi = gi0 + (k << 8); }  // strict >: first index wins
        }
        unsigned long long db  = (unsigned long long)__double_as_longlong(bd); // bd>=0
        unsigned long long key = 0x8000000000000000ull
                               | (db & 0xFFFFFFFFFFFF0000ull)
                               | (unsigned long long)((~bi) & 0xFFFF);
#pragma unroll
        for (int off = 32; off > 0; off >>= 1) {
            unsigned long long o = __shfl_xor(key, off, 64);
            if (o > key) key = o;
        }
        if ((t & 63) == 0) wbest[t >> 6] = key;
        __syncthreads();                                   // bar1
        if (t == 0) {
            unsigned long long k0 = wbest[0];
            if (wbest[1] > k0) k0 = wbest[1];
            if (wbest[2] > k0) k0 = wbest[2];
            if (wbest[3] > k0) k0 = wbest[3];
            __hip_atomic_store(slot_it + wg, k0, __ATOMIC_RELAXED, AGENT);
        }
        if (t < 16) {
            unsigned long long v;
            v = __hip_atomic_load(slot_it + t, __ATOMIC_RELAXED, AGENT);
            while (v == 0) {
                __builtin_amdgcn_s_sleep(1);
                v = __hip_atomic_load(slot_it + t, __ATOMIC_RELAXED, AGENT);
            }
            skey[t] = v;
        }
        __syncthreads();                                   // bar2
        unsigned long long bk = skey[0];
#pragma unroll
        for (int j = 1; j < 16; ++j) if (skey[j] > bk) bk = skey[j];
        int sel = (int)((~bk) & 0xFFFFull);
        cx = (double)P[3*sel+0]; cy = (double)P[3*sel+1]; cz = (double)P[3*sel+2];
        if (wg == 0 && t == 0) {
            float* c = centers + b*(NP*3) + (it+1)*3;
            c[0] = P[3*sel+0]; c[1] = P[3*sel+1]; c[2] = P[3*sel+2];
        }
        slot_it += 16;
        // no trailing barrier: next round's bar1 orders skey/wbest reuse
    }
}

// ---------------------------------------------------------------------------
// KNN pass (R8 structure; R12 top-1 pool). 1024 WGs x 256 thr. blockIdx:
// b=&15 (XCD-local batch), w=(>>4)&15 (center group of 4), s=>>8 (slice of
// 16384). Pass 1: per-thread MIN d2 (fma-chain) -> pool[4][256] -> theta =
// pool 32nd smallest + 4e-3 (pool is a <=1-per-thread subset of true
// distances -> 32nd order stat >= overall 32nd -> all true top-32 pass).
// Pass 2: identical d2, per-lane atomicAdd compaction (order-free). Phase 3:
// exact f64 keys (4/lane), counting-rank top-32 (keys unique -> exact sorted
// positions; >=32 pass -> ranks 0..31 filled) -> gkeys[c][s][32].
// ---------------------------------------------------------------------------
__global__ __launch_bounds__(256, 4)
void knn_pass(const float* __restrict__ pts,
              const float* __restrict__ centers,
              unsigned long long* __restrict__ gkeys)   // [1024][4][32]
{
    const int t    = threadIdx.x;
    const int lane = t & 63;
    const int wid  = t >> 6;             // 0..3
    const int b    = blockIdx.x & 15;
    const int w    = (blockIdx.x >> 4) & 15;
    const int s    = blockIdx.x >> 8;    // 0..3
    const float* __restrict__ P = pts + (size_t)b * NPTS * 3;
    const int sbase = s * SLICE_PTS;
    const float4* __restrict__ P4 = (const float4*)(P + 3 * sbase);

    float m2x[4], m2y[4], m2z[4], c2f[4];
#pragma unroll
    for (int g = 0; g < 4; ++g) {
        int c = b * NP + w * 4 + g;
        float cx = centers[3*c+0], cy = centers[3*c+1], cz = centers[3*c+2];
        c2f[g] = cx*cx + cy*cy + cz*cz;
        m2x[g] = -2.0f*cx; m2y[g] = -2.0f*cy; m2z[g] = -2.0f*cz;
    }

    union PoolKeys {
        unsigned pool[4][256];             // pass1/theta (4 KB)
        unsigned long long keys[4][CAP];   // phase 3 (8 KB) — pool dead by then
    };
    __shared__ PoolKeys pk;
    __shared__ float    theta4[4];
    __shared__ int      cnt4[4];
    __shared__ unsigned idxbuf[4][CAP];    // 4 KB

    // ---- pass 1: per-thread MIN (f32), 4 pts/iter, prefetch k+1 ----
    float s0[4];
#pragma unroll
    for (int g = 0; g < 4; ++g) s0[g] = FLT_MAX;
    {
        float4 A = P4[3*t], B = P4[3*t+1], C = P4[3*t+2];
        for (int k = 0; k < SLICE_PTS/1024; ++k) {       // 16 iterations
            int vb = ((k+1) & 15)*768 + 3*t;             // wrap: last prefetch dropped
            float4 An = P4[vb], Bn = P4[vb+1], Cn = P4[vb+2];
            float qx[4] = {A.x, A.w, B.z, C.y};
            float qy[4] = {A.y, B.x, B.w, C.z};
            float qz[4] = {A.z, B.y, C.x, C.w};
#pragma unroll
            for (int j = 0; j < 4; ++j) {
                float px = qx[j], py = qy[j], pz = qz[j];
                float p2 = px*px + py*py + pz*pz;
#pragma unroll
                for (int g = 0; g < 4; ++g) {
                    float d2 = fmaf(m2x[g], px, fmaf(m2y[g], py, fmaf(m2z[g], pz, c2f[g]))) + p2;
                    s0[g] = fminf(s0[g], d2);
                }
            }
            A = An; B = Bn; C = Cn;
        }
    }
#pragma unroll
    for (int g = 0; g < 4; ++g)
        pk.pool[g][t] = enc32(s0[g]);
    if (t < 4) cnt4[t] = 0;
    __syncthreads();

    // ---- theta: wave wid finds 32nd smallest of pool[wid][0..255] ----
    {
        const int g = wid;
        unsigned e[4];
#pragma unroll
        for (int j = 0; j < 4; ++j) e[j] = pk.pool[g][j * 64 + lane];  // conflict-free
        unsigned ans = 0;
        for (int bit = 31; bit >= 0; --bit) {
            unsigned test = ans | ((1u << bit) - 1u);
            int cnt = 0;
#pragma unroll
            for (int j = 0; j < 4; ++j)
                cnt += (int)__popcll(__ballot(e[j] <= test));
            if (cnt < 32) ans |= (1u << bit);
        }
        if (lane == 0) theta4[g] = dec32(ans) + 4.0e-3f;
    }
    __syncthreads();
    float th[4];
#pragma unroll
    for (int g = 0; g < 4; ++g) th[g] = theta4[g];

    // ---- pass 2: f32 rescan (identical d2), atomicAdd compaction ----
    {
        float4 A = P4[3*t], B = P4[3*t+1], C = P4[3*t+2];
        for (int k = 0; k < SLICE_PTS/1024; ++k) {
            int vb = ((k+1) & 15)*768 + 3*t;
            float4 An = P4[vb], Bn = P4[vb+1], Cn = P4[vb+2];
            float qx[4] = {A.x, A.w, B.z, C.y};
            float qy[4] = {A.y, B.x, B.w, C.z};
            float qz[4] = {A.z, B.y, C.x, C.w};
            int ib = sbase + (k << 10) + (t << 2);
#pragma unroll
            for (int j = 0; j < 4; ++j) {
                float px = qx[j], py = qy[j], pz = qz[j];
                float p2 = px*px + py*py + pz*pz;
#pragma unroll
                for (int g = 0; g < 4; ++g) {
                    float d2 = fmaf(m2x[g], px, fmaf(m2y[g], py, fmaf(m2z[g], pz, c2f[g]))) + p2;
                    if (d2 <= th[g]) {
                        int pos = atomicAdd(&cnt4[g], 1);
                        if (pos < CAP) idxbuf[g][pos] = (unsigned)(ib + j);
                    }
                }
            }
            A = An; B = Bn; C = Cn;
        }
    }
    __syncthreads();   // idxbuf/cnt4 complete; pool dead -> pk.keys reusable

    // ---- phase 3: wave wid -> center wid: f64 keys + counting-rank top-32 ----
    {
        const int g = wid;
        int n = cnt4[g]; if (n > CAP) n = CAP;
        double cxd, cyd, czd, c2d;
        {
#pragma clang fp contract(off)
            cxd = -0.5*(double)m2x[g]; cyd = -0.5*(double)m2y[g]; czd = -0.5*(double)m2z[g];
            c2d = (cxd*cxd + cyd*cyd) + czd*czd;
        }
        unsigned long long rg[4];
#pragma unroll
        for (int j = 0; j < 4; ++j) {
            int p_ = lane + 64*j;
            if (p_ < n) {
                unsigned i = idxbuf[g][p_];
                double d2x;
                {
#pragma clang fp contract(off)
                    double px_ = (double)P[3*i+0];
                    double py_ = (double)P[3*i+1];
                    double pz_ = (double)P[3*i+2];
                    double p2_ = (px_*px_ + py_*py_) + pz_*pz_;
                    double dt_ = (cxd*px_ + cyd*py_) + czd*pz_;
                    d2x = (c2d + p2_) - 2.0*dt_;
                }
                rg[j] = (enc64(d2x) & 0xFFFFFFFFFFFF0000ull)
                      | (unsigned long long)(i & 0xFFFF);
                pk.keys[g][p_] = rg[j];
            } else rg[j] = SENT;
        }
        // same-wave ds_write -> ds_read ordering (compiler inserts lgkmcnt)
        const int c = b * NP + w * 4 + g;
        int rk[4] = {0, 0, 0, 0};
        for (int p = 0; p < n; ++p) {
            unsigned long long kj = pk.keys[g][p];   // broadcast read
            rk[0] += (kj < rg[0]);
            rk[1] += (kj < rg[1]);
            rk[2] += (kj < rg[2]);
            rk[3] += (kj < rg[3]);
        }
        unsigned long long* gout = gkeys + ((size_t)c * SLICES + s) * PS;
#pragma unroll
        for (int j = 0; j < 4; ++j)
            if (lane + 64*j < n && rk[j] < PS) gout[rk[j]] = rg[j];
        // theta guarantees n >= 32 -> ranks 0..31 all filled (keys unique).
    }
}

// ---------------------------------------------------------------------------
// Merge v2 (counting-rank): 256 WGs x 256 thr; wave wid = center
// b*64+grp*4+wid. 128 keys (4 slices x 32, 2/lane) -> LDS; rank = #{keys <
// mine} over 128 (keys unique -> exact sorted position = lax.top_k order);
// rank<32 -> gather P, write patch row 'rank'.
// ---------------------------------------------------------------------------
__global__ __launch_bounds__(256, 4)
void knn_merge(const float* __restrict__ pts,
               const float* __restrict__ centers,
               const unsigned long long* __restrict__ gkeys,
               float* __restrict__ patches)
{
    const int lane = threadIdx.x & 63;
    const int wid  = threadIdx.x >> 6;
    const int b    = blockIdx.x & 15;
    const int grp  = blockIdx.x >> 4;
    const int c    = b * NP + grp * 4 + wid;
    const float* __restrict__ P = pts + (size_t)b * NPTS * 3;

    __shared__ unsigned long long mk[4][SLICES*PS];   // 4 KB

    unsigned long long rg0 = gkeys[(size_t)c * (SLICES*PS) + lane];
    unsigned long long rg1 = gkeys[(size_t)c * (SLICES*PS) + 64 + lane];
    mk[wid][lane]      = rg0;
    mk[wid][64 + lane] = rg1;
    // all 128 entries written by this same wave; wave-internal lgkmcnt orders

    int r0 = 0, r1 = 0;
#pragma unroll 4
    for (int p = 0; p < SLICES*PS; ++p) {
        unsigned long long kj = mk[wid][p];          // broadcast read
        r0 += (kj < rg0);
        r1 += (kj < rg1);
    }

    const float cx = centers[3*c+0], cy = centers[3*c+1], cz = centers[3*c+2];
    if (r0 < PS) {
        int i = (int)(rg0 & 0xFFFFull);
        float* o = patches + (((size_t)c * PS) + r0) * 3;
        o[0] = P[3*i+0] - cx;
        o[1] = P[3*i+1] - cy;
        o[2] = P[3*i+2] - cz;
    }
    if (r1 < PS) {
        int i = (int)(rg1 & 0xFFFFull);
        float* o = patches + (((size_t)c * PS) + r1) * 3;
        o[0] = P[3*i+0] - cx;
        o[1] = P[3*i+1] - cy;
        o[2] = P[3*i+2] - cz;
    }
}

extern "C" void kernel_launch(void* const* d_in, const int* in_sizes, int n_in,
                              void* d_out, int out_size, void* d_ws, size_t ws_size,
                              hipStream_t stream)
{
    const float* pts = (const float*)d_in[0];
    float* out      = (float*)d_out;
    float* patches  = out;                          // [16][64][32][3] = 98304
    float* centers  = out + (size_t)BATCH*NP*PS*3;  // [16][64][3]     = 3072

    unsigned long long* slots = (unsigned long long*)d_ws;                   // 129 KB
    unsigned long long* gkeys = (unsigned long long*)((char*)d_ws + 131072); // 1 MB

    (void)hipMemsetAsync(d_ws, 0, (size_t)BATCH * 63 * 16 * sizeof(unsigned long long), stream);
    fps_kernel<<<dim3(256), dim3(256), 0, stream>>>(pts, centers, slots);
    knn_pass<<<dim3(1024), dim3(256), 0, stream>>>(pts, centers, gkeys);
    knn_merge<<<dim3(256), dim3(256), 0, stream>>>(pts, centers, gkeys, patches);
}